// Round 1
// baseline (441.686 us; speedup 1.0000x reference)
//
#include <hip/hip_runtime.h>

// HierarchicalSoftmax: out[b, c*320 + t] = (x_b · topW[:,c] + top_b[c]) + (x_b · botW[t,:] + bot_b[t])
// B=1024, NHID=128, NCLASSES=320, PER_CLASS=320, row = 102400 fp32.
// Write-bound: 419.4 MB out -> floor ~67 us @ 6.3 TB/s. Prior best 447.2 us (0.94 TB/s) — NOT at roofline.
//
// Restructure vs prior version:
//  * 2 blocks per row (grid 1024x2), 320 threads each -> ~30 waves/CU of store issue (was 16).
//  * Phase-2 thread mapping transposed: each thread owns a FIXED bottom f32x4 (bv in regs),
//    sweeps classes. Inner loop = 1 broadcast ds_read_b32 + 4 v_add + 1 dwordx4 store.
//    (Prior: per-iter ds_read_b128 + magic divide -> lgkmcnt-serialized store stream.)
//  * Plain stores (dropped __builtin_nontemporal_store) — nt unverified, m13's 6.3 TB/s used plain.

#define BATCH       1024
#define NHID        128
#define NCLASSES    320
#define PER_CLASS   320
#define ROW_ELEMS   (NCLASSES * PER_CLASS)    // 102400
#define ROW_F4      (ROW_ELEMS / 4)           // 25600
#define HALVES      2
#define CLS_PER_BLK (NCLASSES / HALVES)       // 160
#define THREADS     320
#define PC_F4       (PER_CLASS / 4)           // 80
#define C_PER_ITER  (THREADS / PC_F4)         // 4 classes per iteration
#define NITER       (CLS_PER_BLK / C_PER_ITER) // 40

typedef float f32x4 __attribute__((ext_vector_type(4)));

__global__ __launch_bounds__(THREADS) void hs_fused_kernel(
    const float* __restrict__ inputs,     // [B, NHID]
    const float* __restrict__ top_W,      // [NHID, NCLASSES] (k-major)
    const float* __restrict__ top_b,      // [NCLASSES]
    const float* __restrict__ bottom_W,   // [PER_CLASS, NHID]
    const float* __restrict__ bottom_b,   // [PER_CLASS] (==NCLASSES here)
    float* __restrict__ out)              // [B, ROW_ELEMS]
{
    __shared__ __align__(16) float s_in[NHID];
    __shared__ float s_top[CLS_PER_BLK];                 // this block's 160 top logits
    __shared__ __align__(16) float s_bot[PER_CLASS];     // all 320 bottom logits

    const int b   = blockIdx.x;   // row
    const int h   = blockIdx.y;   // which half of the classes
    const int tid = threadIdx.x;

    // ---- Phase 0: stage input row ----
    if (tid < NHID) s_in[tid] = inputs[b * NHID + tid];
    __syncthreads();

    // ---- Phase 1: 160 top logits (this half) + all 320 bottom logits ----
    // j in [0,160) -> top class h*160+j ; j in [160,480) -> bottom t = j-160
    for (int j = tid; j < CLS_PER_BLK + PER_CLASS; j += THREADS) {
        float acc;
        if (j < CLS_PER_BLK) {
            const int c = h * CLS_PER_BLK + j;
            acc = top_b[c];
            #pragma unroll 8
            for (int k = 0; k < NHID; ++k)
                acc += s_in[k] * top_W[k * NCLASSES + c];   // coalesced across j
            s_top[j] = acc;
        } else {
            const int t = j - CLS_PER_BLK;
            acc = bottom_b[t];
            const f32x4* w4 = (const f32x4*)(bottom_W + t * NHID);
            #pragma unroll 8
            for (int k4 = 0; k4 < NHID / 4; ++k4) {
                f32x4 w = w4[k4];
                acc += s_in[4 * k4 + 0] * w.x + s_in[4 * k4 + 1] * w.y
                     + s_in[4 * k4 + 2] * w.z + s_in[4 * k4 + 3] * w.w;
            }
            s_bot[t] = acc;
        }
    }
    __syncthreads();

    // ---- Phase 2: stream this half-row (12800 f32x4). ----
    // Thread owns fixed t4 = bottom f32x4 (held in regs); sweeps 4 classes per iteration.
    // Per-iter: 1 broadcast ds_read_b32 (tv) + 4 v_add + 1 global_store_dwordx4.
    const int c_off = tid / PC_F4;            // 0..3 (hoisted divide)
    const int t4    = tid - c_off * PC_F4;    // 0..79
    const f32x4 bv  = ((const f32x4*)s_bot)[t4];

    f32x4* outp = (f32x4*)out
                + (size_t)b * ROW_F4
                + h * (CLS_PER_BLK * PC_F4)   // 12800 f4 per half
                + c_off * PC_F4 + t4;

    #pragma unroll 8
    for (int it = 0; it < NITER; ++it) {
        const float tv = s_top[it * C_PER_ITER + c_off];  // ds_read_b32, 1-2 addr broadcast
        f32x4 v;
        v.x = tv + bv.x;
        v.y = tv + bv.y;
        v.z = tv + bv.z;
        v.w = tv + bv.w;
        outp[it * (C_PER_ITER * PC_F4)] = v;              // contiguous 5 KiB/block-iter
    }
}

extern "C" void kernel_launch(void* const* d_in, const int* in_sizes, int n_in,
                              void* d_out, int out_size, void* d_ws, size_t ws_size,
                              hipStream_t stream) {
    const float* inputs   = (const float*)d_in[0];
    const float* top_W    = (const float*)d_in[1];
    const float* top_b    = (const float*)d_in[2];
    const float* bottom_W = (const float*)d_in[3];
    const float* bottom_b = (const float*)d_in[4];
    float* out = (float*)d_out;

    hs_fused_kernel<<<dim3(BATCH, HALVES), THREADS, 0, stream>>>(
        inputs, top_W, top_b, bottom_W, bottom_b, out);
}